// Round 5
// baseline (187.437 us; speedup 1.0000x reference)
//
#include <hip/hip_runtime.h>
#include <math.h>

#define T_SEQ 4096
#define NBATCH 4
#define NEMBD 1024
#define HS 64
#define BT (NBATCH * T_SEQ)   // 16384

typedef float f32x4 __attribute__((ext_vector_type(4)));
typedef short s8v  __attribute__((ext_vector_type(8)));   // 8 x bf16 bits
typedef short s4v  __attribute__((ext_vector_type(4)));   // 4 x bf16 bits

__device__ __forceinline__ short f2b_rne(float f) {
    union { float f; unsigned u; } v; v.f = f;
    unsigned r = v.u + 0x7fffu + ((v.u >> 16) & 1u);
    return (short)(r >> 16);
}
// pack 2 fp32 -> 2 bf16 (truncate) in one v_perm: low short = lo, high = hi
__device__ __forceinline__ unsigned pk2(float lo, float hi) {
    return __builtin_amdgcn_perm(__float_as_uint(hi), __float_as_uint(lo), 0x07060302u);
}

// ---------------------------------------------------------------------------
// Kernel 0: W{q,k,v} [1024x64] fp32 -> Wt[192][1024] bf16 transposed.
// Softmax scale C^-0.5 * log2(e) folded into Wq (Q comes out pre-scaled).
// ---------------------------------------------------------------------------
__global__ __launch_bounds__(256) void wtrans_kernel(
        const float* __restrict__ Wq, const float* __restrict__ Wk,
        const float* __restrict__ Wv, short* __restrict__ Wt) {
    int e = blockIdx.x * 256 + threadIdx.x;
    int col = e & 63, k = (e >> 6) & 1023, mat = e >> 16;
    const float* W = (mat == 0) ? Wq : ((mat == 1) ? Wk : Wv);
    float scale = (mat == 0) ? 0.0450842298f : 1.0f;   // 2^-5 * log2(e)
    Wt[(size_t)(mat * 64 + col) * 1024 + k] = f2b_rne(W[k * 64 + col] * scale);
}

// ---------------------------------------------------------------------------
// Kernel 1: projections, barrier-free (unchanged from R4; logic re-verified).
// ---------------------------------------------------------------------------
__global__ __launch_bounds__(256) void proj_kernel(
        const float* __restrict__ x, const short* __restrict__ Wt,
        short* __restrict__ QKV) {
    int tid = threadIdx.x;
    int w = tid >> 6, l = tid & 63, quad = l >> 4, c16 = l & 15;
    int row0 = blockIdx.x * 32;
    short* VpT = QKV + 2 * (size_t)BT * HS;   // [64][BT]

    const float* xr0 = x + (size_t)(row0 + c16) * NEMBD;
    const float* xr1 = x + (size_t)(row0 + 16 + c16) * NEMBD;
    const short* wp  = Wt + (size_t)(w * 48 + c16) * 1024;

    f32x4 acc[2][3] = {};
    for (int ko = 0; ko < NEMBD; ko += 32) {
        int off = ko + quad * 8;
        union { s8v v; unsigned u[4]; } a0, a1;
        float4 p0 = *(const float4*)(xr0 + off), p1 = *(const float4*)(xr0 + off + 4);
        a0.u[0] = pk2(p0.x, p0.y); a0.u[1] = pk2(p0.z, p0.w);
        a0.u[2] = pk2(p1.x, p1.y); a0.u[3] = pk2(p1.z, p1.w);
        float4 r0 = *(const float4*)(xr1 + off), r1 = *(const float4*)(xr1 + off + 4);
        a1.u[0] = pk2(r0.x, r0.y); a1.u[1] = pk2(r0.z, r0.w);
        a1.u[2] = pk2(r1.x, r1.y); a1.u[3] = pk2(r1.z, r1.w);
        s8v b0 = *(const s8v*)(wp + off);
        s8v b1 = *(const s8v*)(wp + 16 * 1024 + off);
        s8v b2 = *(const s8v*)(wp + 32 * 1024 + off);
        acc[0][0] = __builtin_amdgcn_mfma_f32_16x16x32_bf16(a0.v, b0, acc[0][0], 0, 0, 0);
        acc[0][1] = __builtin_amdgcn_mfma_f32_16x16x32_bf16(a0.v, b1, acc[0][1], 0, 0, 0);
        acc[0][2] = __builtin_amdgcn_mfma_f32_16x16x32_bf16(a0.v, b2, acc[0][2], 0, 0, 0);
        acc[1][0] = __builtin_amdgcn_mfma_f32_16x16x32_bf16(a1.v, b0, acc[1][0], 0, 0, 0);
        acc[1][1] = __builtin_amdgcn_mfma_f32_16x16x32_bf16(a1.v, b1, acc[1][1], 0, 0, 0);
        acc[1][2] = __builtin_amdgcn_mfma_f32_16x16x32_bf16(a1.v, b2, acc[1][2], 0, 0, 0);
    }
    // epilogue: C/D col=lane&15, row=quad*4+reg [m89]
    #pragma unroll
    for (int rg = 0; rg < 2; rg++)
        #pragma unroll
        for (int j = 0; j < 3; j++) {
            int g = w * 48 + j * 16 + c16;
            int mat = g >> 6, h = g & 63;
            if (mat < 2) {
                #pragma unroll
                for (int r = 0; r < 4; r++) {
                    int row = row0 + rg * 16 + quad * 4 + r;
                    QKV[(size_t)mat * BT * HS + (size_t)row * HS + h] = f2b_rne(acc[rg][j][r]);
                }
            } else {
                s4v pv;
                #pragma unroll
                for (int r = 0; r < 4; r++) pv[r] = f2b_rne(acc[rg][j][r]);
                *(s4v*)(VpT + (size_t)h * BT + row0 + rg * 16 + quad * 4) = pv;
            }
        }
}

// ---------------------------------------------------------------------------
// Kernel 2: causal flash attention.  Block 512 thr = 8 waves sharing 32
// q-rows (2 q-tiles), 8-way key split.  S^T = K*Q^T (K/V frags shared across
// q-tiles).  Fixed-max softmax.  FIX(R4): merge slots are per-LANE
// (4 quads held different rows but wrote one address -> race).  fp32 merge
// done in two qt-phases of 32 KB overlaying the dead P region.
// ---------------------------------------------------------------------------
__global__ __launch_bounds__(512, 4) void attn_kernel(
        const short* __restrict__ QKV, float* __restrict__ out) {
    // 36 KB: K-loop = P[8][2][16][72] shorts; epilogue phases overlay:
    //   O slots 8*4*64*4 = 8192 floats | lsum 8*16 floats at 8192
    __shared__ float smem[9216];
    short* Ps = (short*)smem;

    int tid = threadIdx.x;
    int w = tid >> 6, l = tid & 63, quad = l >> 4, c16 = l & 15;
    int bi = blockIdx.x;
    int b  = bi & 3;
    int jt = 127 - (bi >> 2);      // heavy q-tiles dispatched first
    int q0 = jt * 32;

    const short* Qp  = QKV;
    const short* Kp  = QKV + (size_t)BT * HS;
    const short* VpT = QKV + 2 * (size_t)BT * HS;
    size_t bT = (size_t)b * T_SEQ;

    // Q B-frags (pre-scaled by cs at wtrans): B[k=d][n=qrow=c16]
    s8v qf[2][2];
    #pragma unroll
    for (int qt = 0; qt < 2; qt++)
        #pragma unroll
        for (int h = 0; h < 2; h++)
            qf[qt][h] = *(const s8v*)(Qp + (bT + q0 + qt * 16 + c16) * HS + h * 32 + quad * 8);

    f32x4 o[2][4] = {};
    float lsum[2] = {0.f, 0.f};
    int nkt = (q0 >> 6) + 1;
    short* Pw[2] = { Ps + (w * 2) * 1152, Ps + (w * 2 + 1) * 1152 };

    for (int kt = w; kt < nkt; kt += 8) {
        int kb = kt * 64;
        bool last = (kt == nkt - 1);
        // S^T = K * Q^T : A-frag = K rows (shared across qt)
        f32x4 st[2][4];
        #pragma unroll
        for (int nt = 0; nt < 4; nt++) {
            const short* kr = Kp + (bT + kb + nt * 16 + c16) * HS + quad * 8;
            s8v k0 = *(const s8v*)kr;
            s8v k1 = *(const s8v*)(kr + 32);
            f32x4 z0 = {0.f, 0.f, 0.f, 0.f}, z1 = {0.f, 0.f, 0.f, 0.f};
            z0 = __builtin_amdgcn_mfma_f32_16x16x32_bf16(k0, qf[0][0], z0, 0, 0, 0);
            z0 = __builtin_amdgcn_mfma_f32_16x16x32_bf16(k1, qf[0][1], z0, 0, 0, 0);
            z1 = __builtin_amdgcn_mfma_f32_16x16x32_bf16(k0, qf[1][0], z1, 0, 0, 0);
            z1 = __builtin_amdgcn_mfma_f32_16x16x32_bf16(k1, qf[1][1], z1, 0, 0, 0);
            st[0][nt] = z0; st[1][nt] = z1;
        }
        // exp2 (logits already log2-domain), mask diag tile, lsum, pack P
        #pragma unroll
        for (int qt = 0; qt < 2; qt++) {
            int qrow = q0 + qt * 16 + c16;
            #pragma unroll
            for (int nt = 0; nt < 4; nt++) {
                float p[4];
                #pragma unroll
                for (int r = 0; r < 4; r++) {
                    float v = st[qt][nt][r];
                    if (last && (kb + nt * 16 + quad * 4 + r > qrow)) v = -30000.f;
                    p[r] = __builtin_amdgcn_exp2f(v);
                    lsum[qt] += p[r];
                }
                union { s4v v; unsigned u[2]; } pkv;
                pkv.u[0] = pk2(p[0], p[1]); pkv.u[1] = pk2(p[2], p[3]);
                *(s4v*)(Pw[qt] + c16 * 72 + nt * 16 + quad * 4) = pkv.v;   // P[qrow][key]
            }
        }
        // O += P*V : A = P rows from LDS, B = V^T (shared across qt)
        s8v pa[2][2];
        #pragma unroll
        for (int qt = 0; qt < 2; qt++) {
            pa[qt][0] = *(const s8v*)(Pw[qt] + c16 * 72 + quad * 8);
            pa[qt][1] = *(const s8v*)(Pw[qt] + c16 * 72 + quad * 8 + 32);
        }
        #pragma unroll
        for (int nt = 0; nt < 4; nt++) {
            const short* vr = VpT + (size_t)(nt * 16 + c16) * BT + bT + kb + quad * 8;
            s8v v0 = *(const s8v*)vr;
            s8v v1 = *(const s8v*)(vr + 32);
            #pragma unroll
            for (int qt = 0; qt < 2; qt++) {
                o[qt][nt] = __builtin_amdgcn_mfma_f32_16x16x32_bf16(pa[qt][0], v0, o[qt][nt], 0, 0, 0);
                o[qt][nt] = __builtin_amdgcn_mfma_f32_16x16x32_bf16(pa[qt][1], v1, o[qt][nt], 0, 0, 0);
            }
        }
    }

    // full row-sums: reduce across the 4 quads (rows keyed by c16)
    #pragma unroll
    for (int qt = 0; qt < 2; qt++) {
        lsum[qt] += __shfl_xor(lsum[qt], 16);
        lsum[qt] += __shfl_xor(lsum[qt], 32);
    }

    // two-phase merge; slots are PER-LANE (fixes R4 quad race)
    #pragma unroll
    for (int qt = 0; qt < 2; qt++) {
        __syncthreads();   // phase region (P or previous phase) is dead
        #pragma unroll
        for (int nt = 0; nt < 4; nt++)
            *(f32x4*)(smem + ((w * 4 + nt) * 64 + l) * 4) = o[qt][nt];
        if (l < 16) smem[8192 + w * 16 + l] = lsum[qt];
        __syncthreads();
        if (w < 4) {   // wave w finalizes col-stripe nt=w
            f32x4 os = {0.f, 0.f, 0.f, 0.f}, ls = {0.f, 0.f, 0.f, 0.f};
            #pragma unroll
            for (int s = 0; s < 8; s++) {
                os += *(const f32x4*)(smem + ((s * 4 + w) * 64 + l) * 4);
                ls += *(const f32x4*)(smem + 8192 + s * 16 + quad * 4);
            }
            #pragma unroll
            for (int r = 0; r < 4; r++)
                out[(bT + q0 + qt * 16 + quad * 4 + r) * HS + w * 16 + c16] = os[r] / ls[r];
        }
    }
}

// ---------------------------------------------------------------------------
extern "C" void kernel_launch(void* const* d_in, const int* in_sizes, int n_in,
                              void* d_out, int out_size, void* d_ws, size_t ws_size,
                              hipStream_t stream) {
    const float* x  = (const float*)d_in[0];
    const float* Wq = (const float*)d_in[1];
    const float* Wk = (const float*)d_in[2];
    const float* Wv = (const float*)d_in[3];
    float* out = (float*)d_out;

    short* QKV = (short*)d_ws;                       // Q | K | Vt planes, bf16
    short* Wt  = QKV + (size_t)3 * BT * HS;

    wtrans_kernel<<<768, 256, 0, stream>>>(Wq, Wk, Wv, Wt);
    proj_kernel<<<BT / 32, 256, 0, stream>>>(x, Wt, QKV);
    attn_kernel<<<512, 512, 0, stream>>>(QKV, out);
}

// Round 6
// 185.490 us; speedup vs baseline: 1.0105x; 1.0105x over previous
//
#include <hip/hip_runtime.h>
#include <math.h>

#define T_SEQ 4096
#define NBATCH 4
#define NEMBD 1024
#define HS 64
#define BT (NBATCH * T_SEQ)   // 16384

typedef float f32x4 __attribute__((ext_vector_type(4)));
typedef short s8v  __attribute__((ext_vector_type(8)));   // 8 x bf16 bits
typedef short s4v  __attribute__((ext_vector_type(4)));   // 4 x bf16 bits

__device__ __forceinline__ short f2b_rne(float f) {
    union { float f; unsigned u; } v; v.f = f;
    unsigned r = v.u + 0x7fffu + ((v.u >> 16) & 1u);
    return (short)(r >> 16);
}
// pack 2 fp32 -> 2 bf16 (truncate) in one v_perm: low short = lo, high = hi
__device__ __forceinline__ unsigned pk2(float lo, float hi) {
    return __builtin_amdgcn_perm(__float_as_uint(hi), __float_as_uint(lo), 0x07060302u);
}

// ---------------------------------------------------------------------------
// Kernel 0: W{q,k,v} [1024x64] fp32 -> Wt[192][1024] bf16 transposed.
// Softmax scale C^-0.5 * log2(e) folded into Wq (Q comes out pre-scaled).
// ---------------------------------------------------------------------------
__global__ __launch_bounds__(256) void wtrans_kernel(
        const float* __restrict__ Wq, const float* __restrict__ Wk,
        const float* __restrict__ Wv, short* __restrict__ Wt) {
    int e = blockIdx.x * 256 + threadIdx.x;
    int col = e & 63, k = (e >> 6) & 1023, mat = e >> 16;
    const float* W = (mat == 0) ? Wq : ((mat == 1) ? Wk : Wv);
    float scale = (mat == 0) ? 0.0450842298f : 1.0f;   // 2^-5 * log2(e)
    Wt[(size_t)(mat * 64 + col) * 1024 + k] = f2b_rne(W[k * 64 + col] * scale);
}

// ---------------------------------------------------------------------------
// Kernel 1: projections, REWRITTEN (R6).  R5 read x per-lane row-strided
// (32 cache lines / load inst, 4x redundant across waves) -> latency-bound
// at 60us with every pipe <9%.  Now: block 512 thr = 8 waves, 32 rows x 192
// cols, K-chunk 64; x-chunk staged COALESCED into LDS (thread = one
// contiguous float4; wave = 4 dense rows), fp32->bf16 pack in regs,
// ds_write_b64; next chunk prefetched into regs during compute.  A-frags
// from LDS (stride 72 = 144B, 16B-aligned, 2-way max); W B-frags direct
// global (24 KB/chunk, L1/L2-hot).  Wave (rt,ws): rows rt*16+, cols ws*48+.
// ---------------------------------------------------------------------------
__global__ __launch_bounds__(512, 4) void proj_kernel(
        const float* __restrict__ x, const short* __restrict__ Wt,
        short* __restrict__ QKV) {
    __shared__ short xs[32 * 72];   // 4.5 KB
    int tid = threadIdx.x;
    int w = tid >> 6, l = tid & 63, quad = l >> 4, c16 = l & 15;
    int rt = w >> 2, ws = w & 3;    // row-tile (2), col-group (4 x 48 cols)
    int row0 = blockIdx.x * 32;
    short* VpT = QKV + 2 * (size_t)BT * HS;   // [64][BT]

    // staging: thread covers one float4 of the 32x64 fp32 chunk (coalesced)
    int srow = tid >> 4, skc = (tid & 15) * 4;
    const float* gx = x + (size_t)(row0 + srow) * NEMBD + skc;
    const short* wp = Wt + (size_t)(ws * 48 + c16) * 1024;

    float4 pf = *(const float4*)gx;          // prefetch chunk 0
    f32x4 acc[3] = {};

    for (int ko = 0; ko < NEMBD; ko += 64) {
        {   // commit prefetched chunk to LDS
            union { s4v v; unsigned u[2]; } pkv;
            pkv.u[0] = pk2(pf.x, pf.y); pkv.u[1] = pk2(pf.z, pf.w);
            *(s4v*)(xs + srow * 72 + skc) = pkv.v;
        }
        __syncthreads();
        {   // prefetch next chunk (last iter: reload chunk 0, discarded)
            int kn = (ko + 64 < NEMBD) ? (ko + 64) : 0;
            pf = *(const float4*)(gx + kn);
        }
        #pragma unroll
        for (int ks = 0; ks < 2; ks++) {
            s8v a = *(const s8v*)(xs + (rt * 16 + c16) * 72 + ks * 32 + quad * 8);
            #pragma unroll
            for (int j = 0; j < 3; j++) {
                s8v b = *(const s8v*)(wp + (size_t)j * 16 * 1024 + ko + ks * 32 + quad * 8);
                acc[j] = __builtin_amdgcn_mfma_f32_16x16x32_bf16(a, b, acc[j], 0, 0, 0);
            }
        }
        __syncthreads();
    }
    // epilogue: C/D col=lane&15, row=quad*4+reg [m89]
    #pragma unroll
    for (int j = 0; j < 3; j++) {
        int g = ws * 48 + j * 16 + c16;   // 16-col tiles never straddle mats
        int mat = g >> 6, h = g & 63;
        if (mat < 2) {
            #pragma unroll
            for (int r = 0; r < 4; r++) {
                int row = row0 + rt * 16 + quad * 4 + r;
                QKV[(size_t)mat * BT * HS + (size_t)row * HS + h] = f2b_rne(acc[j][r]);
            }
        } else {   // V: transposed plane, 4 consecutive t -> one b64 store
            s4v pv;
            #pragma unroll
            for (int r = 0; r < 4; r++) pv[r] = f2b_rne(acc[j][r]);
            *(s4v*)(VpT + (size_t)h * BT + row0 + rt * 16 + quad * 4) = pv;
        }
    }
}

// ---------------------------------------------------------------------------
// Kernel 2: causal flash attention (unchanged from R5 — passed, <60us).
// Block 512 thr = 8 waves sharing 32 q-rows (2 q-tiles), 8-way key split.
// S^T = K*Q^T (K/V frags shared across q-tiles).  Fixed-max softmax.
// Per-lane merge slots, two qt-phases overlaying the dead P region.
// ---------------------------------------------------------------------------
__global__ __launch_bounds__(512, 4) void attn_kernel(
        const short* __restrict__ QKV, float* __restrict__ out) {
    // 36 KB: K-loop = P[8][2][16][72] shorts; epilogue phases overlay:
    //   O slots 8*4*64*4 = 8192 floats | lsum 8*16 floats at 8192
    __shared__ float smem[9216];
    short* Ps = (short*)smem;

    int tid = threadIdx.x;
    int w = tid >> 6, l = tid & 63, quad = l >> 4, c16 = l & 15;
    int bi = blockIdx.x;
    int b  = bi & 3;
    int jt = 127 - (bi >> 2);      // heavy q-tiles dispatched first
    int q0 = jt * 32;

    const short* Qp  = QKV;
    const short* Kp  = QKV + (size_t)BT * HS;
    const short* VpT = QKV + 2 * (size_t)BT * HS;
    size_t bT = (size_t)b * T_SEQ;

    // Q B-frags (pre-scaled by cs at wtrans): B[k=d][n=qrow=c16]
    s8v qf[2][2];
    #pragma unroll
    for (int qt = 0; qt < 2; qt++)
        #pragma unroll
        for (int h = 0; h < 2; h++)
            qf[qt][h] = *(const s8v*)(Qp + (bT + q0 + qt * 16 + c16) * HS + h * 32 + quad * 8);

    f32x4 o[2][4] = {};
    float lsum[2] = {0.f, 0.f};
    int nkt = (q0 >> 6) + 1;
    short* Pw[2] = { Ps + (w * 2) * 1152, Ps + (w * 2 + 1) * 1152 };

    for (int kt = w; kt < nkt; kt += 8) {
        int kb = kt * 64;
        bool last = (kt == nkt - 1);
        // S^T = K * Q^T : A-frag = K rows (shared across qt)
        f32x4 st[2][4];
        #pragma unroll
        for (int nt = 0; nt < 4; nt++) {
            const short* kr = Kp + (bT + kb + nt * 16 + c16) * HS + quad * 8;
            s8v k0 = *(const s8v*)kr;
            s8v k1 = *(const s8v*)(kr + 32);
            f32x4 z0 = {0.f, 0.f, 0.f, 0.f}, z1 = {0.f, 0.f, 0.f, 0.f};
            z0 = __builtin_amdgcn_mfma_f32_16x16x32_bf16(k0, qf[0][0], z0, 0, 0, 0);
            z0 = __builtin_amdgcn_mfma_f32_16x16x32_bf16(k1, qf[0][1], z0, 0, 0, 0);
            z1 = __builtin_amdgcn_mfma_f32_16x16x32_bf16(k0, qf[1][0], z1, 0, 0, 0);
            z1 = __builtin_amdgcn_mfma_f32_16x16x32_bf16(k1, qf[1][1], z1, 0, 0, 0);
            st[0][nt] = z0; st[1][nt] = z1;
        }
        // exp2 (logits already log2-domain), mask diag tile, lsum, pack P
        #pragma unroll
        for (int qt = 0; qt < 2; qt++) {
            int qrow = q0 + qt * 16 + c16;
            #pragma unroll
            for (int nt = 0; nt < 4; nt++) {
                float p[4];
                #pragma unroll
                for (int r = 0; r < 4; r++) {
                    float v = st[qt][nt][r];
                    if (last && (kb + nt * 16 + quad * 4 + r > qrow)) v = -30000.f;
                    p[r] = __builtin_amdgcn_exp2f(v);
                    lsum[qt] += p[r];
                }
                union { s4v v; unsigned u[2]; } pkv;
                pkv.u[0] = pk2(p[0], p[1]); pkv.u[1] = pk2(p[2], p[3]);
                *(s4v*)(Pw[qt] + c16 * 72 + nt * 16 + quad * 4) = pkv.v;   // P[qrow][key]
            }
        }
        // O += P*V : A = P rows from LDS, B = V^T (shared across qt)
        s8v pa[2][2];
        #pragma unroll
        for (int qt = 0; qt < 2; qt++) {
            pa[qt][0] = *(const s8v*)(Pw[qt] + c16 * 72 + quad * 8);
            pa[qt][1] = *(const s8v*)(Pw[qt] + c16 * 72 + quad * 8 + 32);
        }
        #pragma unroll
        for (int nt = 0; nt < 4; nt++) {
            const short* vr = VpT + (size_t)(nt * 16 + c16) * BT + bT + kb + quad * 8;
            s8v v0 = *(const s8v*)vr;
            s8v v1 = *(const s8v*)(vr + 32);
            #pragma unroll
            for (int qt = 0; qt < 2; qt++) {
                o[qt][nt] = __builtin_amdgcn_mfma_f32_16x16x32_bf16(pa[qt][0], v0, o[qt][nt], 0, 0, 0);
                o[qt][nt] = __builtin_amdgcn_mfma_f32_16x16x32_bf16(pa[qt][1], v1, o[qt][nt], 0, 0, 0);
            }
        }
    }

    // full row-sums: reduce across the 4 quads (rows keyed by c16)
    #pragma unroll
    for (int qt = 0; qt < 2; qt++) {
        lsum[qt] += __shfl_xor(lsum[qt], 16);
        lsum[qt] += __shfl_xor(lsum[qt], 32);
    }

    // two-phase merge; slots are per-lane (R5 fix)
    #pragma unroll
    for (int qt = 0; qt < 2; qt++) {
        __syncthreads();   // phase region (P or previous phase) is dead
        #pragma unroll
        for (int nt = 0; nt < 4; nt++)
            *(f32x4*)(smem + ((w * 4 + nt) * 64 + l) * 4) = o[qt][nt];
        if (l < 16) smem[8192 + w * 16 + l] = lsum[qt];
        __syncthreads();
        if (w < 4) {   // wave w finalizes col-stripe nt=w
            f32x4 os = {0.f, 0.f, 0.f, 0.f}, ls = {0.f, 0.f, 0.f, 0.f};
            #pragma unroll
            for (int s = 0; s < 8; s++) {
                os += *(const f32x4*)(smem + ((s * 4 + w) * 64 + l) * 4);
                ls += *(const f32x4*)(smem + 8192 + s * 16 + quad * 4);
            }
            #pragma unroll
            for (int r = 0; r < 4; r++)
                out[(bT + q0 + qt * 16 + quad * 4 + r) * HS + w * 16 + c16] = os[r] / ls[r];
        }
    }
}

// ---------------------------------------------------------------------------
extern "C" void kernel_launch(void* const* d_in, const int* in_sizes, int n_in,
                              void* d_out, int out_size, void* d_ws, size_t ws_size,
                              hipStream_t stream) {
    const float* x  = (const float*)d_in[0];
    const float* Wq = (const float*)d_in[1];
    const float* Wk = (const float*)d_in[2];
    const float* Wv = (const float*)d_in[3];
    float* out = (float*)d_out;

    short* QKV = (short*)d_ws;                       // Q | K | Vt planes, bf16
    short* Wt  = QKV + (size_t)3 * BT * HS;

    wtrans_kernel<<<768, 256, 0, stream>>>(Wq, Wk, Wv, Wt);
    proj_kernel<<<BT / 32, 512, 0, stream>>>(x, Wt, QKV);
    attn_kernel<<<512, 512, 0, stream>>>(QKV, out);
}

// Round 7
// 175.588 us; speedup vs baseline: 1.0675x; 1.0564x over previous
//
#include <hip/hip_runtime.h>
#include <math.h>

#define T_SEQ 4096
#define NBATCH 4
#define NEMBD 1024
#define HS 64
#define BT (NBATCH * T_SEQ)   // 16384

typedef float f32x4 __attribute__((ext_vector_type(4)));
typedef short s8v  __attribute__((ext_vector_type(8)));   // 8 x bf16 bits
typedef short s4v  __attribute__((ext_vector_type(4)));   // 4 x bf16 bits

__device__ __forceinline__ short f2b_rne(float f) {
    union { float f; unsigned u; } v; v.f = f;
    unsigned r = v.u + 0x7fffu + ((v.u >> 16) & 1u);
    return (short)(r >> 16);
}
// pack 2 fp32 -> 2 bf16 (truncate) in one v_perm
__device__ __forceinline__ unsigned pk2(float lo, float hi) {
    return __builtin_amdgcn_perm(__float_as_uint(hi), __float_as_uint(lo), 0x07060302u);
}

// ---------------------------------------------------------------------------
// Kernel 0a: linear cast x fp32 -> xb bf16 (HBM-friendly streaming; the GEMM
// then reads xb from L3/L2 where column-slicing costs nothing).
// ---------------------------------------------------------------------------
__global__ __launch_bounds__(256) void xcast_kernel(
        const float* __restrict__ x, short* __restrict__ xb) {
    size_t i = ((size_t)blockIdx.x * 256 + threadIdx.x) * 16;
    float4 a = *(const float4*)(x + i);
    float4 b = *(const float4*)(x + i + 4);
    float4 c = *(const float4*)(x + i + 8);
    float4 d = *(const float4*)(x + i + 12);
    union { s8v v; unsigned u[4]; } v0, v1;
    v0.u[0] = pk2(a.x, a.y); v0.u[1] = pk2(a.z, a.w);
    v0.u[2] = pk2(b.x, b.y); v0.u[3] = pk2(b.z, b.w);
    v1.u[0] = pk2(c.x, c.y); v1.u[1] = pk2(c.z, c.w);
    v1.u[2] = pk2(d.x, d.y); v1.u[3] = pk2(d.z, d.w);
    *(s8v*)(xb + i) = v0.v;
    *(s8v*)(xb + i + 8) = v1.v;
}

// Kernel 0b (fallback if ws too small): linear touch of x to warm L3.
__global__ __launch_bounds__(256) void xtouch_kernel(
        const float* __restrict__ x, float* __restrict__ sink) {
    const float4* p = (const float4*)x;
    float s = 0.f;
    #pragma unroll
    for (int it = 0; it < 8; it++) {
        float4 v = p[(size_t)blockIdx.x * 2048 + it * 256 + threadIdx.x];
        s += v.x + v.y + v.z + v.w;
    }
    if (s == 1.0e38f) sink[0] = s;   // never true; keeps the loads live
}

// ---------------------------------------------------------------------------
// Kernel 1: W{q,k,v} [1024x64] fp32 -> Wt[192][1024] bf16 transposed.
// Softmax scale C^-0.5 * log2(e) folded into Wq.
// ---------------------------------------------------------------------------
__global__ __launch_bounds__(256) void wtrans_kernel(
        const float* __restrict__ Wq, const float* __restrict__ Wk,
        const float* __restrict__ Wv, short* __restrict__ Wt) {
    int e = blockIdx.x * 256 + threadIdx.x;
    int col = e & 63, k = (e >> 6) & 1023, mat = e >> 16;
    const float* W = (mat == 0) ? Wq : ((mat == 1) ? Wk : Wv);
    float scale = (mat == 0) ? 0.0450842298f : 1.0f;   // 2^-5 * log2(e)
    Wt[(size_t)(mat * 64 + col) * 1024 + k] = f2b_rne(W[k * 64 + col] * scale);
}

// ---------------------------------------------------------------------------
// Kernel 2: projections v3 (R7).  R5/R6 were stuck at 60us: x read in
// 256B-per-row column-slices straight from HBM (~25% DRAM row-buffer
// efficiency) + W B-frags re-read from global per wave.  Now: x source is
// bf16 (xcast) or L3-warm fp32 (xtouch); BOTH x and W chunks staged in
// padded LDS (stride 72 -> ~2-way, free).  Block 512 thr = 8 waves,
// 32 rows x 192 cols, BK=64, register prefetch of next chunk.
// ---------------------------------------------------------------------------
template<bool SRC_BF16>
__global__ __launch_bounds__(512) void proj_kernel(
        const void* __restrict__ xsrc, const short* __restrict__ Wt,
        short* __restrict__ QKV) {
    __shared__ short xs[32 * 72];     //  4.6 KB
    __shared__ short wsh[192 * 72];   // 27.6 KB
    int tid = threadIdx.x;
    int w = tid >> 6, l = tid & 63, quad = l >> 4, c16 = l & 15;
    int rt = w >> 2, cg = w & 3;      // row-tile (2 x 16), col-group (4 x 48)
    int row0 = blockIdx.x * 32;
    short* VpT = QKV + 2 * (size_t)BT * HS;   // tiled [b][kt][64 d][64 key]

    // staging addresses
    const short* xb = (const short*)xsrc;
    const float* xf = (const float*)xsrc;
    int xrow_b = tid >> 3,  xc8 = (tid & 7) * 8;    // bf16 path (tid<256)
    int xrow_f = tid >> 4,  xc4 = (tid & 15) * 4;   // fp32 path (all 512)
    int wrow = 0;
    // W chunk: 192 rows x 8 chunks of 8 shorts = 1536 = 512 thr x 3

    // prefetch chunk 0
    s8v  wreg[3];
    s8v  xreg_b;
    float4 xreg_f;
    #pragma unroll
    for (int i = 0; i < 3; i++) {
        int c = tid + 512 * i;
        wreg[i] = *(const s8v*)(Wt + (size_t)(c >> 3) * 1024 + ((c & 7) * 8));
    }
    if (SRC_BF16) {
        if (tid < 256) xreg_b = *(const s8v*)(xb + (size_t)(row0 + xrow_b) * 1024 + xc8);
    } else {
        xreg_f = *(const float4*)(xf + (size_t)(row0 + xrow_f) * 1024 + xc4);
    }

    f32x4 acc[3] = {};
    for (int ko = 0; ko < NEMBD; ko += 64) {
        // commit prefetched chunk to LDS
        #pragma unroll
        for (int i = 0; i < 3; i++) {
            int c = tid + 512 * i;
            *(s8v*)(wsh + (c >> 3) * 72 + ((c & 7) * 8)) = wreg[i];
        }
        if (SRC_BF16) {
            if (tid < 256) *(s8v*)(xs + xrow_b * 72 + xc8) = xreg_b;
        } else {
            union { s4v v; unsigned u[2]; } pkv;
            pkv.u[0] = pk2(xreg_f.x, xreg_f.y);
            pkv.u[1] = pk2(xreg_f.z, xreg_f.w);
            *(s4v*)(xs + xrow_f * 72 + xc4) = pkv.v;
        }
        __syncthreads();
        {   // prefetch next chunk (wraps to 0 on last iter; discarded)
            int kn = (ko + 64 < NEMBD) ? (ko + 64) : 0;
            #pragma unroll
            for (int i = 0; i < 3; i++) {
                int c = tid + 512 * i;
                wreg[i] = *(const s8v*)(Wt + (size_t)(c >> 3) * 1024 + kn + ((c & 7) * 8));
            }
            if (SRC_BF16) {
                if (tid < 256) xreg_b = *(const s8v*)(xb + (size_t)(row0 + xrow_b) * 1024 + kn + xc8);
            } else {
                xreg_f = *(const float4*)(xf + (size_t)(row0 + xrow_f) * 1024 + kn + xc4);
            }
        }
        #pragma unroll
        for (int ks = 0; ks < 2; ks++) {
            s8v a = *(const s8v*)(xs + (rt * 16 + c16) * 72 + ks * 32 + quad * 8);
            #pragma unroll
            for (int j = 0; j < 3; j++) {
                s8v b = *(const s8v*)(wsh + (cg * 48 + j * 16 + c16) * 72 + ks * 32 + quad * 8);
                acc[j] = __builtin_amdgcn_mfma_f32_16x16x32_bf16(a, b, acc[j], 0, 0, 0);
            }
        }
        __syncthreads();
    }
    // epilogue: C/D col=lane&15, row=quad*4+reg [m89]
    #pragma unroll
    for (int j = 0; j < 3; j++) {
        int g = cg * 48 + j * 16 + c16;
        int mat = g >> 6, h = g & 63;
        if (mat < 2) {
            #pragma unroll
            for (int r = 0; r < 4; r++) {
                int row = row0 + rt * 16 + quad * 4 + r;
                QKV[(size_t)mat * BT * HS + (size_t)row * HS + h] = f2b_rne(acc[j][r]);
            }
        } else {   // V: tiled-transposed plane [b][tile][d][key]
            int tg = row0 + rt * 16 + quad * 4;
            int b = tg >> 12, t = tg & 4095;
            size_t base = (((size_t)((b * 64 + (t >> 6)) * 64 + h)) << 6) + (t & 63);
            s4v pv;
            #pragma unroll
            for (int r = 0; r < 4; r++) pv[r] = f2b_rne(acc[j][r]);
            *(s4v*)(VpT + base) = pv;
        }
    }
}

// ---------------------------------------------------------------------------
// Kernel 3: causal flash attention (structure as R5/R6; V^T now TILED so V
// B-frag loads hit a dense 2KB window like K's).  Block 512 thr = 8 waves
// sharing 32 q-rows (2 q-tiles), 8-way key split, fixed-max softmax,
// per-lane merge slots in two qt-phases.
// ---------------------------------------------------------------------------
__global__ __launch_bounds__(512, 4) void attn_kernel(
        const short* __restrict__ QKV, float* __restrict__ out) {
    __shared__ float smem[9216];   // 36 KB: P regions; epilogue overlays
    short* Ps = (short*)smem;

    int tid = threadIdx.x;
    int w = tid >> 6, l = tid & 63, quad = l >> 4, c16 = l & 15;
    int bi = blockIdx.x;
    int b  = bi & 3;
    int jt = 127 - (bi >> 2);      // heavy q-tiles dispatched first
    int q0 = jt * 32;

    const short* Qp  = QKV;
    const short* Kp  = QKV + (size_t)BT * HS;
    const short* VpT = QKV + 2 * (size_t)BT * HS;   // tiled
    size_t bT = (size_t)b * T_SEQ;

    s8v qf[2][2];
    #pragma unroll
    for (int qt = 0; qt < 2; qt++)
        #pragma unroll
        for (int h = 0; h < 2; h++)
            qf[qt][h] = *(const s8v*)(Qp + (bT + q0 + qt * 16 + c16) * HS + h * 32 + quad * 8);

    f32x4 o[2][4] = {};
    float lsum[2] = {0.f, 0.f};
    int nkt = (q0 >> 6) + 1;
    short* Pw[2] = { Ps + (w * 2) * 1152, Ps + (w * 2 + 1) * 1152 };

    for (int kt = w; kt < nkt; kt += 8) {
        int kb = kt * 64;
        bool last = (kt == nkt - 1);
        // S^T = K * Q^T : A-frag = K rows (shared across qt)
        f32x4 st[2][4];
        #pragma unroll
        for (int nt = 0; nt < 4; nt++) {
            const short* kr = Kp + (bT + kb + nt * 16 + c16) * HS + quad * 8;
            s8v k0 = *(const s8v*)kr;
            s8v k1 = *(const s8v*)(kr + 32);
            f32x4 z0 = {0.f, 0.f, 0.f, 0.f}, z1 = {0.f, 0.f, 0.f, 0.f};
            z0 = __builtin_amdgcn_mfma_f32_16x16x32_bf16(k0, qf[0][0], z0, 0, 0, 0);
            z0 = __builtin_amdgcn_mfma_f32_16x16x32_bf16(k1, qf[0][1], z0, 0, 0, 0);
            z1 = __builtin_amdgcn_mfma_f32_16x16x32_bf16(k0, qf[1][0], z1, 0, 0, 0);
            z1 = __builtin_amdgcn_mfma_f32_16x16x32_bf16(k1, qf[1][1], z1, 0, 0, 0);
            st[0][nt] = z0; st[1][nt] = z1;
        }
        // exp2 (log2-domain logits), diag mask, lsum, pack P
        #pragma unroll
        for (int qt = 0; qt < 2; qt++) {
            int qrow = q0 + qt * 16 + c16;
            #pragma unroll
            for (int nt = 0; nt < 4; nt++) {
                float p[4];
                #pragma unroll
                for (int r = 0; r < 4; r++) {
                    float v = st[qt][nt][r];
                    if (last && (kb + nt * 16 + quad * 4 + r > qrow)) v = -30000.f;
                    p[r] = __builtin_amdgcn_exp2f(v);
                    lsum[qt] += p[r];
                }
                union { s4v v; unsigned u[2]; } pkv;
                pkv.u[0] = pk2(p[0], p[1]); pkv.u[1] = pk2(p[2], p[3]);
                *(s4v*)(Pw[qt] + c16 * 72 + nt * 16 + quad * 4) = pkv.v;
            }
        }
        // O += P*V : A = P rows from LDS, B = V^T tiled (shared across qt)
        s8v pa[2][2];
        #pragma unroll
        for (int qt = 0; qt < 2; qt++) {
            pa[qt][0] = *(const s8v*)(Pw[qt] + c16 * 72 + quad * 8);
            pa[qt][1] = *(const s8v*)(Pw[qt] + c16 * 72 + quad * 8 + 32);
        }
        #pragma unroll
        for (int nt = 0; nt < 4; nt++) {
            const short* vr = VpT + (((size_t)((b * 64 + kt) * 64 + nt * 16 + c16)) << 6) + quad * 8;
            s8v v0 = *(const s8v*)vr;
            s8v v1 = *(const s8v*)(vr + 32);
            #pragma unroll
            for (int qt = 0; qt < 2; qt++) {
                o[qt][nt] = __builtin_amdgcn_mfma_f32_16x16x32_bf16(pa[qt][0], v0, o[qt][nt], 0, 0, 0);
                o[qt][nt] = __builtin_amdgcn_mfma_f32_16x16x32_bf16(pa[qt][1], v1, o[qt][nt], 0, 0, 0);
            }
        }
    }

    #pragma unroll
    for (int qt = 0; qt < 2; qt++) {
        lsum[qt] += __shfl_xor(lsum[qt], 16);
        lsum[qt] += __shfl_xor(lsum[qt], 32);
    }

    // two-phase per-lane merge (R5 fix)
    #pragma unroll
    for (int qt = 0; qt < 2; qt++) {
        __syncthreads();
        #pragma unroll
        for (int nt = 0; nt < 4; nt++)
            *(f32x4*)(smem + ((w * 4 + nt) * 64 + l) * 4) = o[qt][nt];
        if (l < 16) smem[8192 + w * 16 + l] = lsum[qt];
        __syncthreads();
        if (w < 4) {
            f32x4 os = {0.f, 0.f, 0.f, 0.f}, ls = {0.f, 0.f, 0.f, 0.f};
            #pragma unroll
            for (int s = 0; s < 8; s++) {
                os += *(const f32x4*)(smem + ((s * 4 + w) * 64 + l) * 4);
                ls += *(const f32x4*)(smem + 8192 + s * 16 + quad * 4);
            }
            #pragma unroll
            for (int r = 0; r < 4; r++)
                out[(bT + q0 + qt * 16 + quad * 4 + r) * HS + w * 16 + c16] = os[r] / ls[r];
        }
    }
}

// ---------------------------------------------------------------------------
extern "C" void kernel_launch(void* const* d_in, const int* in_sizes, int n_in,
                              void* d_out, int out_size, void* d_ws, size_t ws_size,
                              hipStream_t stream) {
    const float* x  = (const float*)d_in[0];
    const float* Wq = (const float*)d_in[1];
    const float* Wk = (const float*)d_in[2];
    const float* Wv = (const float*)d_in[3];
    float* out = (float*)d_out;

    // ws: QKV planes (6.3 MB) | Wt (384 KB) | xb (32 MB, optional)
    short* QKV = (short*)d_ws;
    short* Wt  = QKV + (size_t)3 * BT * HS;
    short* xb  = Wt + (size_t)192 * 1024;
    size_t need = ((size_t)3 * BT * HS + (size_t)192 * 1024 + (size_t)BT * NEMBD) * 2;

    wtrans_kernel<<<768, 256, 0, stream>>>(Wq, Wk, Wv, Wt);
    if (ws_size >= need) {
        xcast_kernel<<<4096, 256, 0, stream>>>(x, xb);
        proj_kernel<true><<<BT / 32, 512, 0, stream>>>(xb, Wt, QKV);
    } else {
        xtouch_kernel<<<2048, 256, 0, stream>>>(x, (float*)d_ws);
        proj_kernel<false><<<BT / 32, 512, 0, stream>>>(x, Wt, QKV);
    }
    attn_kernel<<<512, 512, 0, stream>>>(QKV, out);
}

// Round 8
// 169.240 us; speedup vs baseline: 1.1075x; 1.0375x over previous
//
#include <hip/hip_runtime.h>
#include <math.h>

#define T_SEQ 4096
#define NBATCH 4
#define NEMBD 1024
#define HS 64
#define BT (NBATCH * T_SEQ)   // 16384

typedef float f32x4 __attribute__((ext_vector_type(4)));
typedef short s8v  __attribute__((ext_vector_type(8)));   // 8 x bf16 bits
typedef short s4v  __attribute__((ext_vector_type(4)));   // 4 x bf16 bits

__device__ __forceinline__ short f2b_rne(float f) {
    union { float f; unsigned u; } v; v.f = f;
    unsigned r = v.u + 0x7fffu + ((v.u >> 16) & 1u);
    return (short)(r >> 16);
}
// pack 2 fp32 -> 2 bf16 (truncate) in one v_perm
__device__ __forceinline__ unsigned pk2(float lo, float hi) {
    return __builtin_amdgcn_perm(__float_as_uint(hi), __float_as_uint(lo), 0x07060302u);
}

// ---------------------------------------------------------------------------
// Kernel 0a: linear cast x fp32 -> xb bf16 (HBM-friendly streaming).
// ---------------------------------------------------------------------------
__global__ __launch_bounds__(256) void xcast_kernel(
        const float* __restrict__ x, short* __restrict__ xb) {
    size_t i = ((size_t)blockIdx.x * 256 + threadIdx.x) * 16;
    float4 a = *(const float4*)(x + i);
    float4 b = *(const float4*)(x + i + 4);
    float4 c = *(const float4*)(x + i + 8);
    float4 d = *(const float4*)(x + i + 12);
    union { s8v v; unsigned u[4]; } v0, v1;
    v0.u[0] = pk2(a.x, a.y); v0.u[1] = pk2(a.z, a.w);
    v0.u[2] = pk2(b.x, b.y); v0.u[3] = pk2(b.z, b.w);
    v1.u[0] = pk2(c.x, c.y); v1.u[1] = pk2(c.z, c.w);
    v1.u[2] = pk2(d.x, d.y); v1.u[3] = pk2(d.z, d.w);
    *(s8v*)(xb + i) = v0.v;
    *(s8v*)(xb + i + 8) = v1.v;
}

// Kernel 0b (fallback if ws too small): linear touch of x to warm L3.
__global__ __launch_bounds__(256) void xtouch_kernel(
        const float* __restrict__ x, float* __restrict__ sink) {
    const float4* p = (const float4*)x;
    float s = 0.f;
    #pragma unroll
    for (int it = 0; it < 8; it++) {
        float4 v = p[(size_t)blockIdx.x * 2048 + it * 256 + threadIdx.x];
        s += v.x + v.y + v.z + v.w;
    }
    if (s == 1.0e38f) sink[0] = s;
}

// ---------------------------------------------------------------------------
// Kernel 1: W{q,k,v} [1024x64] fp32 -> Wt[192][1024] bf16 transposed.
// Softmax scale C^-0.5 * log2(e) folded into Wq.
// ---------------------------------------------------------------------------
__global__ __launch_bounds__(256) void wtrans_kernel(
        const float* __restrict__ Wq, const float* __restrict__ Wk,
        const float* __restrict__ Wv, short* __restrict__ Wt) {
    int e = blockIdx.x * 256 + threadIdx.x;
    int col = e & 63, k = (e >> 6) & 1023, mat = e >> 16;
    const float* W = (mat == 0) ? Wq : ((mat == 1) ? Wk : Wv);
    float scale = (mat == 0) ? 0.0450842298f : 1.0f;   // 2^-5 * log2(e)
    Wt[(size_t)(mat * 64 + col) * 1024 + k] = f2b_rne(W[k * 64 + col] * scale);
}

// ---------------------------------------------------------------------------
// Kernel 2: projections v3 (unchanged from R7 — no longer the top dispatch).
// ---------------------------------------------------------------------------
template<bool SRC_BF16>
__global__ __launch_bounds__(512) void proj_kernel(
        const void* __restrict__ xsrc, const short* __restrict__ Wt,
        short* __restrict__ QKV) {
    __shared__ short xs[32 * 72];
    __shared__ short wsh[192 * 72];
    int tid = threadIdx.x;
    int w = tid >> 6, l = tid & 63, quad = l >> 4, c16 = l & 15;
    int rt = w >> 2, cg = w & 3;
    int row0 = blockIdx.x * 32;
    short* VpT = QKV + 2 * (size_t)BT * HS;   // tiled [b][kt][64 d][64 key]

    const short* xb = (const short*)xsrc;
    const float* xf = (const float*)xsrc;
    int xrow_b = tid >> 3,  xc8 = (tid & 7) * 8;
    int xrow_f = tid >> 4,  xc4 = (tid & 15) * 4;

    s8v  wreg[3];
    s8v  xreg_b;
    float4 xreg_f;
    #pragma unroll
    for (int i = 0; i < 3; i++) {
        int c = tid + 512 * i;
        wreg[i] = *(const s8v*)(Wt + (size_t)(c >> 3) * 1024 + ((c & 7) * 8));
    }
    if (SRC_BF16) {
        if (tid < 256) xreg_b = *(const s8v*)(xb + (size_t)(row0 + xrow_b) * 1024 + xc8);
    } else {
        xreg_f = *(const float4*)(xf + (size_t)(row0 + xrow_f) * 1024 + xc4);
    }

    f32x4 acc[3] = {};
    for (int ko = 0; ko < NEMBD; ko += 64) {
        #pragma unroll
        for (int i = 0; i < 3; i++) {
            int c = tid + 512 * i;
            *(s8v*)(wsh + (c >> 3) * 72 + ((c & 7) * 8)) = wreg[i];
        }
        if (SRC_BF16) {
            if (tid < 256) *(s8v*)(xs + xrow_b * 72 + xc8) = xreg_b;
        } else {
            union { s4v v; unsigned u[2]; } pkv;
            pkv.u[0] = pk2(xreg_f.x, xreg_f.y);
            pkv.u[1] = pk2(xreg_f.z, xreg_f.w);
            *(s4v*)(xs + xrow_f * 72 + xc4) = pkv.v;
        }
        __syncthreads();
        {
            int kn = (ko + 64 < NEMBD) ? (ko + 64) : 0;
            #pragma unroll
            for (int i = 0; i < 3; i++) {
                int c = tid + 512 * i;
                wreg[i] = *(const s8v*)(Wt + (size_t)(c >> 3) * 1024 + kn + ((c & 7) * 8));
            }
            if (SRC_BF16) {
                if (tid < 256) xreg_b = *(const s8v*)(xb + (size_t)(row0 + xrow_b) * 1024 + kn + xc8);
            } else {
                xreg_f = *(const float4*)(xf + (size_t)(row0 + xrow_f) * 1024 + kn + xc4);
            }
        }
        #pragma unroll
        for (int ks = 0; ks < 2; ks++) {
            s8v a = *(const s8v*)(xs + (rt * 16 + c16) * 72 + ks * 32 + quad * 8);
            #pragma unroll
            for (int j = 0; j < 3; j++) {
                s8v b = *(const s8v*)(wsh + (cg * 48 + j * 16 + c16) * 72 + ks * 32 + quad * 8);
                acc[j] = __builtin_amdgcn_mfma_f32_16x16x32_bf16(a, b, acc[j], 0, 0, 0);
            }
        }
        __syncthreads();
    }
    #pragma unroll
    for (int j = 0; j < 3; j++) {
        int g = cg * 48 + j * 16 + c16;
        int mat = g >> 6, h = g & 63;
        if (mat < 2) {
            #pragma unroll
            for (int r = 0; r < 4; r++) {
                int row = row0 + rt * 16 + quad * 4 + r;
                QKV[(size_t)mat * BT * HS + (size_t)row * HS + h] = f2b_rne(acc[j][r]);
            }
        } else {
            int tg = row0 + rt * 16 + quad * 4;
            int b = tg >> 12, t = tg & 4095;
            size_t base = (((size_t)((b * 64 + (t >> 6)) * 64 + h)) << 6) + (t & 63);
            s4v pv;
            #pragma unroll
            for (int r = 0; r < 4; r++) pv[r] = f2b_rne(acc[j][r]);
            *(s4v*)(VpT + base) = pv;
        }
    }
}

// ---------------------------------------------------------------------------
// Kernel 3: causal flash attention.  R8: K-loop rephased for latency —
// R7 loaded K frags per-nt right before their MFMAs and V frags after the
// softmax, paying ~8 serialized L2/L3 waits (~900cyc) per tile = ~8k cyc/tile
// (matches 56us).  Now: phase 1 issues ALL 8 K loads (one wait), phase 3
// issues ALL 8 V loads right after the S-MFMAs so exp2+pack+LDS-roundtrip
// (~600cyc) hides them.  K regs die before V regs peak -> ~128 total, still
// 4 waves/SIMD at (512,4).
// ---------------------------------------------------------------------------
__global__ __launch_bounds__(512, 4) void attn_kernel(
        const short* __restrict__ QKV, float* __restrict__ out) {
    __shared__ float smem[9216];   // 36 KB: P regions; epilogue overlays
    short* Ps = (short*)smem;

    int tid = threadIdx.x;
    int w = tid >> 6, l = tid & 63, quad = l >> 4, c16 = l & 15;
    int bi = blockIdx.x;
    int b  = bi & 3;
    int jt = 127 - (bi >> 2);      // heavy q-tiles dispatched first
    int q0 = jt * 32;

    const short* Qp  = QKV;
    const short* Kp  = QKV + (size_t)BT * HS;
    const short* VpT = QKV + 2 * (size_t)BT * HS;   // tiled
    size_t bT = (size_t)b * T_SEQ;

    s8v qf[2][2];
    #pragma unroll
    for (int qt = 0; qt < 2; qt++)
        #pragma unroll
        for (int h = 0; h < 2; h++)
            qf[qt][h] = *(const s8v*)(Qp + (bT + q0 + qt * 16 + c16) * HS + h * 32 + quad * 8);

    f32x4 o[2][4] = {};
    float lsum[2] = {0.f, 0.f};
    int nkt = (q0 >> 6) + 1;
    short* Pw[2] = { Ps + (w * 2) * 1152, Ps + (w * 2 + 1) * 1152 };
    const short* kbase = Kp + (bT + c16) * HS + quad * 8;
    const short* vbase = VpT + (((size_t)((b * 64) * 64 + c16)) << 6) + quad * 8;

    for (int kt = w; kt < nkt; kt += 8) {
        int kb = kt * 64;
        bool last = (kt == nkt - 1);

        // ---- phase 1: issue ALL K fragment loads (8 x b128, one wait) ----
        s8v kf[4][2];
        #pragma unroll
        for (int nt = 0; nt < 4; nt++) {
            const short* kr = kbase + (size_t)(kb + nt * 16) * HS;
            kf[nt][0] = *(const s8v*)kr;
            kf[nt][1] = *(const s8v*)(kr + 32);
        }
        // ---- phase 2: S^T = K * Q^T ----
        f32x4 st[2][4];
        #pragma unroll
        for (int nt = 0; nt < 4; nt++) {
            f32x4 z0 = {0.f, 0.f, 0.f, 0.f}, z1 = {0.f, 0.f, 0.f, 0.f};
            z0 = __builtin_amdgcn_mfma_f32_16x16x32_bf16(kf[nt][0], qf[0][0], z0, 0, 0, 0);
            z0 = __builtin_amdgcn_mfma_f32_16x16x32_bf16(kf[nt][1], qf[0][1], z0, 0, 0, 0);
            z1 = __builtin_amdgcn_mfma_f32_16x16x32_bf16(kf[nt][0], qf[1][0], z1, 0, 0, 0);
            z1 = __builtin_amdgcn_mfma_f32_16x16x32_bf16(kf[nt][1], qf[1][1], z1, 0, 0, 0);
            st[0][nt] = z0; st[1][nt] = z1;
        }
        // ---- phase 3: issue ALL V fragment loads (hidden by softmax) ----
        s8v vf[4][2];
        #pragma unroll
        for (int nt = 0; nt < 4; nt++) {
            const short* vr = vbase + (((size_t)(kt * 64 + nt * 16)) << 6);
            vf[nt][0] = *(const s8v*)vr;
            vf[nt][1] = *(const s8v*)(vr + 32);
        }
        // ---- phase 4: exp2, diag mask, lsum, pack P -> LDS ----
        #pragma unroll
        for (int qt = 0; qt < 2; qt++) {
            int qrow = q0 + qt * 16 + c16;
            #pragma unroll
            for (int nt = 0; nt < 4; nt++) {
                float p[4];
                #pragma unroll
                for (int r = 0; r < 4; r++) {
                    float v = st[qt][nt][r];
                    if (last && (kb + nt * 16 + quad * 4 + r > qrow)) v = -30000.f;
                    p[r] = __builtin_amdgcn_exp2f(v);
                    lsum[qt] += p[r];
                }
                union { s4v v; unsigned u[2]; } pkv;
                pkv.u[0] = pk2(p[0], p[1]); pkv.u[1] = pk2(p[2], p[3]);
                *(s4v*)(Pw[qt] + c16 * 72 + nt * 16 + quad * 4) = pkv.v;
            }
        }
        // ---- phase 5: P A-frags from LDS; phase 6: PV MFMAs ----
        s8v pa[2][2];
        #pragma unroll
        for (int qt = 0; qt < 2; qt++) {
            pa[qt][0] = *(const s8v*)(Pw[qt] + c16 * 72 + quad * 8);
            pa[qt][1] = *(const s8v*)(Pw[qt] + c16 * 72 + quad * 8 + 32);
        }
        #pragma unroll
        for (int nt = 0; nt < 4; nt++)
            #pragma unroll
            for (int qt = 0; qt < 2; qt++) {
                o[qt][nt] = __builtin_amdgcn_mfma_f32_16x16x32_bf16(pa[qt][0], vf[nt][0], o[qt][nt], 0, 0, 0);
                o[qt][nt] = __builtin_amdgcn_mfma_f32_16x16x32_bf16(pa[qt][1], vf[nt][1], o[qt][nt], 0, 0, 0);
            }
    }

    #pragma unroll
    for (int qt = 0; qt < 2; qt++) {
        lsum[qt] += __shfl_xor(lsum[qt], 16);
        lsum[qt] += __shfl_xor(lsum[qt], 32);
    }

    // two-phase per-lane merge (R5 fix)
    #pragma unroll
    for (int qt = 0; qt < 2; qt++) {
        __syncthreads();
        #pragma unroll
        for (int nt = 0; nt < 4; nt++)
            *(f32x4*)(smem + ((w * 4 + nt) * 64 + l) * 4) = o[qt][nt];
        if (l < 16) smem[8192 + w * 16 + l] = lsum[qt];
        __syncthreads();
        if (w < 4) {
            f32x4 os = {0.f, 0.f, 0.f, 0.f}, ls = {0.f, 0.f, 0.f, 0.f};
            #pragma unroll
            for (int s = 0; s < 8; s++) {
                os += *(const f32x4*)(smem + ((s * 4 + w) * 64 + l) * 4);
                ls += *(const f32x4*)(smem + 8192 + s * 16 + quad * 4);
            }
            #pragma unroll
            for (int r = 0; r < 4; r++)
                out[(bT + q0 + qt * 16 + quad * 4 + r) * HS + w * 16 + c16] = os[r] / ls[r];
        }
    }
}

// ---------------------------------------------------------------------------
extern "C" void kernel_launch(void* const* d_in, const int* in_sizes, int n_in,
                              void* d_out, int out_size, void* d_ws, size_t ws_size,
                              hipStream_t stream) {
    const float* x  = (const float*)d_in[0];
    const float* Wq = (const float*)d_in[1];
    const float* Wk = (const float*)d_in[2];
    const float* Wv = (const float*)d_in[3];
    float* out = (float*)d_out;

    short* QKV = (short*)d_ws;
    short* Wt  = QKV + (size_t)3 * BT * HS;
    short* xb  = Wt + (size_t)192 * 1024;
    size_t need = ((size_t)3 * BT * HS + (size_t)192 * 1024 + (size_t)BT * NEMBD) * 2;

    wtrans_kernel<<<768, 256, 0, stream>>>(Wq, Wk, Wv, Wt);
    if (ws_size >= need) {
        xcast_kernel<<<4096, 256, 0, stream>>>(x, xb);
        proj_kernel<true><<<BT / 32, 512, 0, stream>>>(xb, Wt, QKV);
    } else {
        xtouch_kernel<<<2048, 256, 0, stream>>>(x, (float*)d_ws);
        proj_kernel<false><<<BT / 32, 512, 0, stream>>>(x, Wt, QKV);
    }
    attn_kernel<<<512, 512, 0, stream>>>(QKV, out);
}